// Round 10
// baseline (259.636 us; speedup 1.0000x reference)
//
#include <hip/hip_runtime.h>
#include <hip/hip_fp16.h>

// GCN: h1 = relu(Agg(x@W1)+b1); h2 = relu(Agg(h1@W2)+b2); out = mean(h2)@Wc+bc
// norm(r,c)=dinv[r]*dinv[c] factors: GEMM epilogue prescales rows by dinv[r],
// agg sums fp16 rows, scales by dinv[c] at the end.
// R1: agg MLP (88->57). R2/R3/R4: scattered global atomics = hard ~16 G/s
// ceiling. R5: one-pass bucket + gemm fusion (339). R6: interleave + fp16 (272).
// R7: zero-atomic CSR build (254). R8: prefix-in-LDS scatter + dinv prescale
// (k_fuse 62->49; total neutral — bottleneck moved to aggs/gemm2/front-end).
// R9: (a) MFMA fp16 GEMMs, A-frags straight from global (A[m=lane&15][k=quad*8+j]),
//     B-frags from pre-transposed fp16 Wt[n][k]; no LDS, no barriers;
//     (b) HB=64 front-end (hist 3.2MB, 64-step colscan);
//     (c) half-range 2-pass scatter => 25KB LDS => k_fuse 6 blocks/CU.

typedef _Float16 half8 __attribute__((ext_vector_type(8)));
typedef float f32x4 __attribute__((ext_vector_type(4)));

constexpr int N = 50000;
constexpr int E = 800000;
constexpr int D = 128;
constexpr int DOUT = 40;
constexpr int CAP = 64;               // slots/node (Poisson(16) tail ~1e-18)
constexpr int HB = 64;                // histogram chunks
constexpr int EPB = E / HB;           // 12500 edges/chunk
constexpr int HALFN = 25000;          // scatter half-range (25KB LDS)
constexpr int HWW = HALFN / 4;        // 6250 words
constexpr int GM = (N + 127) / 128;   // 391 gemm blocks
constexpr int NW = N / 4;             // 12500 agg blocks
constexpr int GF = 459;               // fuse grid: 66 scatter slots + 393 gemm

// ---------------- Phase A: per-chunk LDS histogram ----------------
__global__ __launch_bounds__(1024) void k_hist(const int* __restrict__ col,
                                               unsigned char* __restrict__ hist) {
    __shared__ unsigned int h[12500];
    int b = blockIdx.x, t = threadIdx.x;
    for (int i = t; i < 12500; i += 1024) h[i] = 0;
    __syncthreads();
    int e0 = b * EPB;
    for (int e = e0 + t; e < e0 + EPB; e += 1024) {
        int c = col[e];
        atomicAdd(&h[c >> 2], 1u << ((c & 3) * 8));
    }
    __syncthreads();
    unsigned int* out = (unsigned int*)(hist + (size_t)b * 50000);
    for (int i = t; i < 12500; i += 1024) out[i] = h[i];
}

// ---------------- Phase B: per-node prefix over chunks; deg + dinv ---------
__global__ void k_colscan(unsigned char* __restrict__ hist, int* __restrict__ deg,
                          float* __restrict__ dinv) {
    int c = blockIdx.x * 256 + threadIdx.x;
    if (c >= N) return;
    int sum = 0;
#pragma unroll 4
    for (int b = 0; b < HB; ++b) {
        size_t idx = (size_t)b * 50000 + c;
        int v = hist[idx];
        hist[idx] = (unsigned char)sum;   // exclusive prefix (deg<=255)
        sum += v;
    }
    deg[c] = sum;
    dinv[c] = rsqrtf((float)(sum + 1));   // +1 self loop
}

// ---------------- W transpose+cast: Wt[n][k] = fp16(W[k][n]) ----------------
__global__ __launch_bounds__(256) void k_wt(const float* __restrict__ W1,
                                            const float* __restrict__ W2,
                                            __half* __restrict__ T1,
                                            __half* __restrict__ T2) {
    int b = blockIdx.x;                  // 32 blocks, 16 per matrix
    const float* W = (b < 16) ? W1 : W2;
    __half* T = (b < 16) ? T1 : T2;
    int base = (b & 15) * 1024;
    for (int o = base + threadIdx.x; o < base + 1024; o += 256) {
        int n = o >> 7, k = o & 127;
        T[o] = (__half)W[k * 128 + n];
    }
}

// ---------------- MFMA GEMM: outH[r] = fp16(dinv[r] * (A[r] @ W)) ----------
// Wave handles 32 rows x 128 cols; A-frag per lane = 8 contiguous k-halves of
// row m0+(lane&15) at k = kq*32 + quad*8 (one 16B load). B-frag from Wt[n][k].
__device__ __forceinline__ half8 ldA(const float* rowp, int koff) {
    float4 u0 = *(const float4*)(rowp + koff);
    float4 u1 = *(const float4*)(rowp + koff + 4);
    half8 r;
    r[0] = (_Float16)u0.x; r[1] = (_Float16)u0.y;
    r[2] = (_Float16)u0.z; r[3] = (_Float16)u0.w;
    r[4] = (_Float16)u1.x; r[5] = (_Float16)u1.y;
    r[6] = (_Float16)u1.z; r[7] = (_Float16)u1.w;
    return r;
}
__device__ __forceinline__ half8 ldA(const __half* rowp, int koff) {
    return *(const half8*)(rowp + koff);
}

template <typename TA>
__device__ __forceinline__ void mfma_gemm(const TA* __restrict__ A,
                                          const __half* __restrict__ Wt,
                                          const float* __restrict__ dinv,
                                          __half* __restrict__ outH,
                                          int row0, int tid) {
    int wave = tid >> 6, lane = tid & 63;
    int quad = lane >> 4, c16 = lane & 15;
    int m0 = row0 + wave * 32;
    int ra = m0 + c16;      if (ra >= N) ra = 0;   // OOB rows: dummy read row 0
    int rb = m0 + 16 + c16; if (rb >= N) rb = 0;
    const TA* pa = A + (size_t)ra * D;
    const TA* pb = A + (size_t)rb * D;

    f32x4 acc[2][8];
#pragma unroll
    for (int i = 0; i < 2; ++i)
#pragma unroll
        for (int j = 0; j < 8; ++j) acc[i][j] = (f32x4){0.f, 0.f, 0.f, 0.f};

#pragma unroll
    for (int kq = 0; kq < 4; ++kq) {
        int koff = kq * 32 + quad * 8;
        half8 a0 = ldA(pa, koff);
        half8 a1 = ldA(pb, koff);
#pragma unroll
        for (int nt = 0; nt < 8; ++nt) {
            half8 bf = *(const half8*)(Wt + (size_t)(nt * 16 + c16) * D + koff);
            acc[0][nt] = __builtin_amdgcn_mfma_f32_16x16x32_f16(a0, bf, acc[0][nt], 0, 0, 0);
            acc[1][nt] = __builtin_amdgcn_mfma_f32_16x16x32_f16(a1, bf, acc[1][nt], 0, 0, 0);
        }
    }

    // C/D: col = lane&15, row = quad*4 + reg (dtype-independent, m89/m91)
#pragma unroll
    for (int rt = 0; rt < 2; ++rt) {
        int mt = m0 + rt * 16;
#pragma unroll
        for (int i = 0; i < 4; ++i) {
            int grow = mt + quad * 4 + i;
            if (grow < N) {
                float s = dinv[grow];
                __half* orow = outH + (size_t)grow * D + c16;
#pragma unroll
                for (int nt = 0; nt < 8; ++nt)
                    orow[nt * 16] = (__half)(acc[rt][nt][i] * s);
            }
        }
    }
}

// ---------------- Phase C fused: half-range rank-scatter + GEMM-1 ----------
__global__ __launch_bounds__(256) void k_fuse(const int* __restrict__ ei,
                                              const unsigned char* __restrict__ hist,
                                              unsigned short* __restrict__ csr,
                                              const float* __restrict__ x,
                                              const __half* __restrict__ Wt1,
                                              const float* __restrict__ dinv,
                                              __half* __restrict__ outH) {
    __shared__ unsigned int h[HWW];      // 25KB (scatter blocks only)
    int b = blockIdx.x;
    if (b % 7 == 0) {
        int sb = b / 7;
        if (sb >= HB) return;
        int t = threadIdx.x;
        int e0 = sb * EPB;
        const unsigned int* prefw = (const unsigned int*)(hist + (size_t)sb * 50000);
        for (int hf = 0; hf < 2; ++hf) {
            int cbase = hf * HALFN;
            for (int i = t; i < HWW; i += 256) h[i] = prefw[cbase / 4 + i];
            __syncthreads();
            for (int e = e0 + t; e < e0 + EPB; e += 256) {
                int c = ei[E + e];
                unsigned int cl = (unsigned int)(c - cbase);
                if (cl < (unsigned int)HALFN) {
                    int r = ei[e];
                    unsigned int old = atomicAdd(&h[cl >> 2], 1u << ((c & 3) * 8));
                    int slot = (old >> ((c & 3) * 8)) & 0xff;
                    if (slot < CAP) csr[(c << 6) + slot] = (unsigned short)r;
                }
            }
            __syncthreads();
        }
        return;
    }
    int gb = b - (b / 7 + 1);
    if (gb >= GM) return;
    mfma_gemm<float>(x, Wt1, dinv, outH, gb * 128, threadIdx.x);
}

// ---------------- GEMM layer 2 (fp16 A) ----------------
__global__ __launch_bounds__(256) void k_gemm(const __half* __restrict__ A,
                                              const __half* __restrict__ Wt,
                                              const float* __restrict__ dinv,
                                              __half* __restrict__ outH) {
    mfma_gemm<__half>(A, Wt, dinv, outH, blockIdx.x * 128, threadIdx.x);
}

// ---------------- Aggregation core (1 wave/node, fp16 row-sum) -------------
__device__ __forceinline__ void add8(float* a, uint4 u) {
    __half2* hp = (__half2*)&u;
#pragma unroll
    for (int i = 0; i < 4; ++i) {
        float2 f = __half22float2(hp[i]);
        a[2 * i]     += f.x;
        a[2 * i + 1] += f.y;
    }
}

__device__ __forceinline__ float agg_core(int c, int lane,
                                          const __half* __restrict__ hsH,
                                          const int* __restrict__ deg,
                                          const unsigned short* __restrict__ csr,
                                          float* a0) {
    int qw = lane >> 4;         // 0..3: edge within group of 4
    int q  = lane & 15;         // column group: halves q*8..q*8+7
    int dgRaw = deg[c];
    int dg = dgRaw < CAP ? dgRaw : CAP;
    float dc = rsqrtf((float)(dgRaw + 1));
    int e0 = c << 6;

    float a1[8] = {0, 0, 0, 0, 0, 0, 0, 0};
#pragma unroll
    for (int t = 0; t < 8; ++t) a0[t] = 0.f;
    if (qw == 0)                // self loop (hsH[c] already = dinv[c]*h[c])
        add8(a0, *(const uint4*)&hsH[(size_t)c * D + q * 8]);

    int j = 0;
    for (; j + 8 <= dg; j += 8) {
        int r0 = csr[e0 + j + qw];
        int r1 = csr[e0 + j + 4 + qw];
        uint4 u0 = *(const uint4*)&hsH[(size_t)r0 * D + q * 8];
        uint4 u1 = *(const uint4*)&hsH[(size_t)r1 * D + q * 8];
        add8(a0, u0);
        add8(a1, u1);
    }
    if (j + 4 <= dg) {
        int r0 = csr[e0 + j + qw];
        add8(a0, *(const uint4*)&hsH[(size_t)r0 * D + q * 8]);
        j += 4;
    }
    int rem = dg - j;
    if (qw < rem) {
        int r0 = csr[e0 + j + qw];
        add8(a0, *(const uint4*)&hsH[(size_t)r0 * D + q * 8]);
    }

#pragma unroll
    for (int t = 0; t < 8; ++t) a0[t] += a1[t];
#pragma unroll
    for (int t = 0; t < 8; ++t) a0[t] += __shfl_xor(a0[t], 16, 64);
#pragma unroll
    for (int t = 0; t < 8; ++t) a0[t] += __shfl_xor(a0[t], 32, 64);
    return dc;
}

// layer-1 agg: writes fp16 rows (unscaled h1; gemm2 scales its own output)
__global__ __launch_bounds__(256) void k_agg1(const __half* __restrict__ hsH,
                                              const int* __restrict__ deg,
                                              const unsigned short* __restrict__ csr,
                                              const float* __restrict__ bias,
                                              __half* __restrict__ outH) {
    int wave = threadIdx.x >> 6;
    int lane = threadIdx.x & 63;
    int c = blockIdx.x * 4 + wave;
    float a0[8];
    float dc = agg_core(c, lane, hsH, deg, csr, a0);
    if ((lane >> 4) == 0) {
        int q = lane & 15;
        union { __half2 h[4]; uint4 u; } p;
#pragma unroll
        for (int i = 0; i < 4; ++i) {
            float xv = fmaxf(fmaf(dc, a0[2 * i],     bias[q * 8 + 2 * i]),     0.f);
            float yv = fmaxf(fmaf(dc, a0[2 * i + 1], bias[q * 8 + 2 * i + 1]), 0.f);
            p.h[i] = __floats2half2_rn(xv, yv);
        }
        *(uint4*)&outH[(size_t)c * D + q * 8] = p.u;
    }
}

// layer-2 agg: reduces h2 rows straight into per-block pool partials
__global__ __launch_bounds__(256) void k_agg2(const __half* __restrict__ hsH,
                                              const int* __restrict__ deg,
                                              const unsigned short* __restrict__ csr,
                                              const float* __restrict__ bias,
                                              float* __restrict__ gpart) {
    __shared__ float gblk[4][128];
    int wave = threadIdx.x >> 6;
    int lane = threadIdx.x & 63;
    int c = blockIdx.x * 4 + wave;
    float a0[8];
    float dc = agg_core(c, lane, hsH, deg, csr, a0);
    if ((lane >> 4) == 0) {
        int q = lane & 15;
#pragma unroll
        for (int i = 0; i < 8; ++i)
            gblk[wave][q * 8 + i] = fmaxf(fmaf(dc, a0[i], bias[q * 8 + i]), 0.f);
    }
    __syncthreads();
    int t = threadIdx.x;
    if (t < 128)
        gpart[(size_t)blockIdx.x * 128 + t] =
            gblk[0][t] + gblk[1][t] + gblk[2][t] + gblk[3][t];
}

// ---------------- Pool stage 2: 12500 partials -> 256 partials --------------
__global__ __launch_bounds__(256) void k_pool(const float* __restrict__ gpart,
                                              float* __restrict__ gpart2) {
    int d = threadIdx.x & 127;
    int half = threadIdx.x >> 7;
    int b = blockIdx.x;                 // 256 blocks
    int per = (NW + 255) / 256;         // 49
    int r0 = b * per;
    int r1 = r0 + per;
    if (r1 > NW) r1 = NW;
    float acc = 0.f;
    for (int r = r0 + half; r < r1; r += 2)
        acc += gpart[(size_t)r * D + d];
    __shared__ float red[256];
    red[threadIdx.x] = acc;
    __syncthreads();
    if (half == 0) gpart2[(size_t)b * D + d] = red[d] + red[128 + d];
}

// ---------------- Final: g = sum(gpart2)/N; out = g@Wc + bc ----------------
__global__ __launch_bounds__(512) void k_final(const float* __restrict__ gpart2,
                                               const float* __restrict__ Wc,
                                               const float* __restrict__ bc,
                                               float* __restrict__ out) {
    __shared__ float g[D];
    __shared__ float red[512];
    int t = threadIdx.x;
    int d = t & 127, grp = t >> 7;
    float s = 0.f;
#pragma unroll 4
    for (int w = grp * 64; w < grp * 64 + 64; ++w)
        s += gpart2[(size_t)w * D + d];
    red[t] = s;
    __syncthreads();
    if (grp == 0)
        g[d] = (red[d] + red[128 + d] + red[256 + d] + red[384 + d]) * (1.0f / (float)N);
    __syncthreads();
    if (t < DOUT) {
        float acc = bc[t];
        for (int dd = 0; dd < D; ++dd) acc = fmaf(g[dd], Wc[dd * DOUT + t], acc);
        out[t] = acc;
    }
}

extern "C" void kernel_launch(void* const* d_in, const int* in_sizes, int n_in,
                              void* d_out, int out_size, void* d_ws, size_t ws_size,
                              hipStream_t stream) {
    const float* x  = (const float*)d_in[0];
    const int*   ei = (const int*)d_in[1];
    const float* W1 = (const float*)d_in[2];
    const float* b1 = (const float*)d_in[3];
    const float* W2 = (const float*)d_in[4];
    const float* b2 = (const float*)d_in[5];
    const float* Wc = (const float*)d_in[6];
    const float* bc = (const float*)d_in[7];
    float* out = (float*)d_out;

    char* ws = (char*)d_ws;
    size_t off = 0;
    auto alloc = [&](size_t bytes) {
        void* p = ws + off;
        off += (bytes + 511) & ~(size_t)511;
        return p;
    };
    unsigned char*  hist   = (unsigned char*) alloc((size_t)HB * 50000);     // 3.2MB
    int*            deg    = (int*)           alloc((size_t)N * 4);
    float*          dinv   = (float*)         alloc((size_t)N * 4);
    unsigned short* csr    = (unsigned short*)alloc((size_t)N * CAP * 2);    // 6.4MB
    __half*         hsH    = (__half*)        alloc((size_t)N * D * 2);      // 12.8MB
    __half*         hactH  = (__half*)        alloc((size_t)N * D * 2);      // 12.8MB
    __half*         Wt1    = (__half*)        alloc((size_t)D * D * 2);      // 32KB
    __half*         Wt2    = (__half*)        alloc((size_t)D * D * 2);      // 32KB
    float*          gpart  = (float*)         alloc((size_t)NW * D * 4);     // 6.4MB
    float*          gpart2 = (float*)         alloc((size_t)256 * D * 4);
    (void)ws_size; (void)in_sizes; (void)n_in; (void)out_size;

    const int* col = ei + E;

    k_wt<<<32, 256, 0, stream>>>(W1, W2, Wt1, Wt2);
    k_hist<<<HB, 1024, 0, stream>>>(col, hist);
    k_colscan<<<(N + 255) / 256, 256, 0, stream>>>(hist, deg, dinv);
    // scatter (every 7th block) + MFMA gemm layer 1
    k_fuse<<<GF, 256, 0, stream>>>(ei, hist, csr, x, Wt1, dinv, hsH);

    k_agg1<<<NW, 256, 0, stream>>>(hsH, deg, csr, b1, hactH);
    k_gemm<<<GM, 256, 0, stream>>>(hactH, Wt2, dinv, hsH);
    k_agg2<<<NW, 256, 0, stream>>>(hsH, deg, csr, b2, gpart);
    k_pool<<<256, 256, 0, stream>>>(gpart, gpart2);
    k_final<<<1, 512, 0, stream>>>(gpart2, Wc, bc, out);
}

// Round 11
// 229.630 us; speedup vs baseline: 1.1307x; 1.1307x over previous
//
#include <hip/hip_runtime.h>
#include <hip/hip_fp16.h>

// GCN: h1 = relu(Agg(x@W1)+b1); h2 = relu(Agg(h1@W2)+b2); out = mean(h2)@Wc+bc
// norm(r,c)=dinv[r]*dinv[c] factors: GEMM epilogue prescales rows by dinv[r],
// agg sums fp16 rows, scales by dinv[c] at the end.
// R1: agg MLP (88->57). R2-R4: scattered global atomics = hard ~16 G/s ceiling.
// R5: one-pass bucket + fusion (339). R6: interleave + fp16 (272).
// R7: zero-atomic CSR build (254). R8: prefix-in-LDS scatter (k_fuse 49).
// R9: MFMA fp16 gemms (correct, absmax 2.4e-4) BUT 64-block 2-pass scatter
//     => 75us long-tail REGRESSION (occ 5.8%).
// R10: rank-at-count: k_hist's LDS atomicAdd return IS the edge's in-chunk
//     rank — store rank[e] (coalesced byte). Scatter needs no LDS/ownership:
//     slot = hist_pref[chunk][c] + rank[e]; fully parallel, x4 ILP, fused 2:1
//     with MFMA gemm1. HB=128.

typedef _Float16 half8 __attribute__((ext_vector_type(8)));
typedef float f32x4 __attribute__((ext_vector_type(4)));

constexpr int N = 50000;
constexpr int E = 800000;
constexpr int D = 128;
constexpr int DOUT = 40;
constexpr int CAP = 64;               // slots/node (Poisson(16) tail ~1e-18)
constexpr int HB = 128;               // histogram chunks
constexpr int EPB = E / HB;           // 6250 edges/chunk
constexpr int HWRD = 12500;           // 50000 bytes = 12500 words
constexpr int GM = (N + 127) / 128;   // 391 gemm blocks
constexpr int NW = N / 4;             // 12500 agg blocks
constexpr int T4 = E / 4;             // 200000 scatter threads
constexpr int GB = (T4 + 255) / 256;  // 782 scatter blocks
constexpr int GF = 3 * GM;            // 1173 = 782 scatter + 391 gemm

// ---------------- Phase A: per-chunk LDS histogram + per-edge rank ---------
__global__ __launch_bounds__(1024) void k_hist(const int* __restrict__ col,
                                               unsigned char* __restrict__ hist,
                                               unsigned char* __restrict__ rank) {
    __shared__ unsigned int h[HWRD];
    int b = blockIdx.x, t = threadIdx.x;
    for (int i = t; i < HWRD; i += 1024) h[i] = 0;
    __syncthreads();
    int e0 = b * EPB;
    for (int e = e0 + t; e < e0 + EPB; e += 1024) {
        int c = col[e];
        unsigned int old = atomicAdd(&h[c >> 2], 1u << ((c & 3) * 8));
        rank[e] = (unsigned char)((old >> ((c & 3) * 8)) & 0xff);
    }
    __syncthreads();
    unsigned int* out = (unsigned int*)(hist + (size_t)b * 50000);
    for (int i = t; i < HWRD; i += 1024) out[i] = h[i];
}

// ---------------- Phase B: per-node prefix over chunks; deg + dinv ---------
__global__ void k_colscan(unsigned char* __restrict__ hist, int* __restrict__ deg,
                          float* __restrict__ dinv) {
    int c = blockIdx.x * 256 + threadIdx.x;
    if (c >= N) return;
    int sum = 0;
#pragma unroll 4
    for (int b = 0; b < HB; ++b) {
        size_t idx = (size_t)b * 50000 + c;
        int v = hist[idx];
        hist[idx] = (unsigned char)sum;   // exclusive prefix (deg<=255)
        sum += v;
    }
    deg[c] = sum;
    dinv[c] = rsqrtf((float)(sum + 1));   // +1 self loop
}

// ---------------- W transpose+cast: Wt[n][k] = fp16(W[k][n]) ----------------
__global__ __launch_bounds__(256) void k_wt(const float* __restrict__ W1,
                                            const float* __restrict__ W2,
                                            __half* __restrict__ T1,
                                            __half* __restrict__ T2) {
    int b = blockIdx.x;                  // 32 blocks, 16 per matrix
    const float* W = (b < 16) ? W1 : W2;
    __half* T = (b < 16) ? T1 : T2;
    int base = (b & 15) * 1024;
    for (int o = base + threadIdx.x; o < base + 1024; o += 256) {
        int n = o >> 7, k = o & 127;
        T[o] = (__half)W[k * 128 + n];
    }
}

// ---------------- MFMA GEMM: outH[r] = fp16(dinv[r] * (A[r] @ W)) ----------
__device__ __forceinline__ half8 ldA(const float* rowp, int koff) {
    float4 u0 = *(const float4*)(rowp + koff);
    float4 u1 = *(const float4*)(rowp + koff + 4);
    half8 r;
    r[0] = (_Float16)u0.x; r[1] = (_Float16)u0.y;
    r[2] = (_Float16)u0.z; r[3] = (_Float16)u0.w;
    r[4] = (_Float16)u1.x; r[5] = (_Float16)u1.y;
    r[6] = (_Float16)u1.z; r[7] = (_Float16)u1.w;
    return r;
}
__device__ __forceinline__ half8 ldA(const __half* rowp, int koff) {
    return *(const half8*)(rowp + koff);
}

template <typename TA>
__device__ __forceinline__ void mfma_gemm(const TA* __restrict__ A,
                                          const __half* __restrict__ Wt,
                                          const float* __restrict__ dinv,
                                          __half* __restrict__ outH,
                                          int row0, int tid) {
    int wave = tid >> 6, lane = tid & 63;
    int quad = lane >> 4, c16 = lane & 15;
    int m0 = row0 + wave * 32;
    int ra = m0 + c16;      if (ra >= N) ra = 0;   // OOB rows: dummy read row 0
    int rb = m0 + 16 + c16; if (rb >= N) rb = 0;
    const TA* pa = A + (size_t)ra * D;
    const TA* pb = A + (size_t)rb * D;

    f32x4 acc[2][8];
#pragma unroll
    for (int i = 0; i < 2; ++i)
#pragma unroll
        for (int j = 0; j < 8; ++j) acc[i][j] = (f32x4){0.f, 0.f, 0.f, 0.f};

#pragma unroll
    for (int kq = 0; kq < 4; ++kq) {
        int koff = kq * 32 + quad * 8;
        half8 a0 = ldA(pa, koff);
        half8 a1 = ldA(pb, koff);
#pragma unroll
        for (int nt = 0; nt < 8; ++nt) {
            half8 bf = *(const half8*)(Wt + (size_t)(nt * 16 + c16) * D + koff);
            acc[0][nt] = __builtin_amdgcn_mfma_f32_16x16x32_f16(a0, bf, acc[0][nt], 0, 0, 0);
            acc[1][nt] = __builtin_amdgcn_mfma_f32_16x16x32_f16(a1, bf, acc[1][nt], 0, 0, 0);
        }
    }

    // C/D: col = lane&15, row = quad*4 + reg
#pragma unroll
    for (int rt = 0; rt < 2; ++rt) {
        int mt = m0 + rt * 16;
#pragma unroll
        for (int i = 0; i < 4; ++i) {
            int grow = mt + quad * 4 + i;
            if (grow < N) {
                float s = dinv[grow];
                __half* orow = outH + (size_t)grow * D + c16;
#pragma unroll
                for (int nt = 0; nt < 8; ++nt)
                    orow[nt * 16] = (__half)(acc[rt][nt][i] * s);
            }
        }
    }
}

// ---------------- Phase C fused: parallel rank-scatter + GEMM-1 -------------
__global__ __launch_bounds__(256) void k_fuse(const int* __restrict__ ei,
                                              const unsigned char* __restrict__ hist,
                                              const unsigned char* __restrict__ rank,
                                              unsigned short* __restrict__ csr,
                                              const float* __restrict__ x,
                                              const __half* __restrict__ Wt1,
                                              const float* __restrict__ dinv,
                                              __half* __restrict__ outH) {
    int b = blockIdx.x, m = b % 3;
    if (m < 2) {
        // ---- scatter: fully parallel, slot = pref[chunk][c] + rank[e] ----
        int sb = (b / 3) * 2 + m;
        int t = sb * 256 + threadIdx.x;
        if (t >= T4) return;
#pragma unroll
        for (int i = 0; i < 4; ++i) {
            int e = t + i * T4;
            int c = ei[E + e];
            int r = ei[e];
            int chunk = e / EPB;
            int slot = (int)hist[(size_t)chunk * 50000 + c] + (int)rank[e];
            if (slot < CAP) csr[(c << 6) + slot] = (unsigned short)r;
        }
        return;
    }
    // ---- gemm branch ----
    mfma_gemm<float>(x, Wt1, dinv, outH, (b / 3) * 128, threadIdx.x);
}

// ---------------- GEMM layer 2 (fp16 A) ----------------
__global__ __launch_bounds__(256) void k_gemm(const __half* __restrict__ A,
                                              const __half* __restrict__ Wt,
                                              const float* __restrict__ dinv,
                                              __half* __restrict__ outH) {
    mfma_gemm<__half>(A, Wt, dinv, outH, blockIdx.x * 128, threadIdx.x);
}

// ---------------- Aggregation core (1 wave/node, fp16 row-sum) -------------
__device__ __forceinline__ void add8(float* a, uint4 u) {
    __half2* hp = (__half2*)&u;
#pragma unroll
    for (int i = 0; i < 4; ++i) {
        float2 f = __half22float2(hp[i]);
        a[2 * i]     += f.x;
        a[2 * i + 1] += f.y;
    }
}

__device__ __forceinline__ float agg_core(int c, int lane,
                                          const __half* __restrict__ hsH,
                                          const int* __restrict__ deg,
                                          const unsigned short* __restrict__ csr,
                                          float* a0) {
    int qw = lane >> 4;         // 0..3: edge within group of 4
    int q  = lane & 15;         // column group: halves q*8..q*8+7
    int dgRaw = deg[c];
    int dg = dgRaw < CAP ? dgRaw : CAP;
    float dc = rsqrtf((float)(dgRaw + 1));
    int e0 = c << 6;

    float a1[8] = {0, 0, 0, 0, 0, 0, 0, 0};
#pragma unroll
    for (int t = 0; t < 8; ++t) a0[t] = 0.f;
    if (qw == 0)                // self loop (hsH[c] already = dinv[c]*h[c])
        add8(a0, *(const uint4*)&hsH[(size_t)c * D + q * 8]);

    int j = 0;
    for (; j + 8 <= dg; j += 8) {
        int r0 = csr[e0 + j + qw];
        int r1 = csr[e0 + j + 4 + qw];
        uint4 u0 = *(const uint4*)&hsH[(size_t)r0 * D + q * 8];
        uint4 u1 = *(const uint4*)&hsH[(size_t)r1 * D + q * 8];
        add8(a0, u0);
        add8(a1, u1);
    }
    if (j + 4 <= dg) {
        int r0 = csr[e0 + j + qw];
        add8(a0, *(const uint4*)&hsH[(size_t)r0 * D + q * 8]);
        j += 4;
    }
    int rem = dg - j;
    if (qw < rem) {
        int r0 = csr[e0 + j + qw];
        add8(a0, *(const uint4*)&hsH[(size_t)r0 * D + q * 8]);
    }

#pragma unroll
    for (int t = 0; t < 8; ++t) a0[t] += a1[t];
#pragma unroll
    for (int t = 0; t < 8; ++t) a0[t] += __shfl_xor(a0[t], 16, 64);
#pragma unroll
    for (int t = 0; t < 8; ++t) a0[t] += __shfl_xor(a0[t], 32, 64);
    return dc;
}

// layer-1 agg: writes fp16 rows (unscaled h1; gemm2 scales its own output)
__global__ __launch_bounds__(256) void k_agg1(const __half* __restrict__ hsH,
                                              const int* __restrict__ deg,
                                              const unsigned short* __restrict__ csr,
                                              const float* __restrict__ bias,
                                              __half* __restrict__ outH) {
    int wave = threadIdx.x >> 6;
    int lane = threadIdx.x & 63;
    int c = blockIdx.x * 4 + wave;
    float a0[8];
    float dc = agg_core(c, lane, hsH, deg, csr, a0);
    if ((lane >> 4) == 0) {
        int q = lane & 15;
        union { __half2 h[4]; uint4 u; } p;
#pragma unroll
        for (int i = 0; i < 4; ++i) {
            float xv = fmaxf(fmaf(dc, a0[2 * i],     bias[q * 8 + 2 * i]),     0.f);
            float yv = fmaxf(fmaf(dc, a0[2 * i + 1], bias[q * 8 + 2 * i + 1]), 0.f);
            p.h[i] = __floats2half2_rn(xv, yv);
        }
        *(uint4*)&outH[(size_t)c * D + q * 8] = p.u;
    }
}

// layer-2 agg: reduces h2 rows straight into per-block pool partials
__global__ __launch_bounds__(256) void k_agg2(const __half* __restrict__ hsH,
                                              const int* __restrict__ deg,
                                              const unsigned short* __restrict__ csr,
                                              const float* __restrict__ bias,
                                              float* __restrict__ gpart) {
    __shared__ float gblk[4][128];
    int wave = threadIdx.x >> 6;
    int lane = threadIdx.x & 63;
    int c = blockIdx.x * 4 + wave;
    float a0[8];
    float dc = agg_core(c, lane, hsH, deg, csr, a0);
    if ((lane >> 4) == 0) {
        int q = lane & 15;
#pragma unroll
        for (int i = 0; i < 8; ++i)
            gblk[wave][q * 8 + i] = fmaxf(fmaf(dc, a0[i], bias[q * 8 + i]), 0.f);
    }
    __syncthreads();
    int t = threadIdx.x;
    if (t < 128)
        gpart[(size_t)blockIdx.x * 128 + t] =
            gblk[0][t] + gblk[1][t] + gblk[2][t] + gblk[3][t];
}

// ---------------- Pool stage 2: 12500 partials -> 256 partials --------------
__global__ __launch_bounds__(256) void k_pool(const float* __restrict__ gpart,
                                              float* __restrict__ gpart2) {
    int d = threadIdx.x & 127;
    int half = threadIdx.x >> 7;
    int b = blockIdx.x;                 // 256 blocks
    int per = (NW + 255) / 256;         // 49
    int r0 = b * per;
    int r1 = r0 + per;
    if (r1 > NW) r1 = NW;
    float acc = 0.f;
    for (int r = r0 + half; r < r1; r += 2)
        acc += gpart[(size_t)r * D + d];
    __shared__ float red[256];
    red[threadIdx.x] = acc;
    __syncthreads();
    if (half == 0) gpart2[(size_t)b * D + d] = red[d] + red[128 + d];
}

// ---------------- Final: g = sum(gpart2)/N; out = g@Wc + bc ----------------
__global__ __launch_bounds__(512) void k_final(const float* __restrict__ gpart2,
                                               const float* __restrict__ Wc,
                                               const float* __restrict__ bc,
                                               float* __restrict__ out) {
    __shared__ float g[D];
    __shared__ float red[512];
    int t = threadIdx.x;
    int d = t & 127, grp = t >> 7;
    float s = 0.f;
#pragma unroll 4
    for (int w = grp * 64; w < grp * 64 + 64; ++w)
        s += gpart2[(size_t)w * D + d];
    red[t] = s;
    __syncthreads();
    if (grp == 0)
        g[d] = (red[d] + red[128 + d] + red[256 + d] + red[384 + d]) * (1.0f / (float)N);
    __syncthreads();
    if (t < DOUT) {
        float acc = bc[t];
        for (int dd = 0; dd < D; ++dd) acc = fmaf(g[dd], Wc[dd * DOUT + t], acc);
        out[t] = acc;
    }
}

extern "C" void kernel_launch(void* const* d_in, const int* in_sizes, int n_in,
                              void* d_out, int out_size, void* d_ws, size_t ws_size,
                              hipStream_t stream) {
    const float* x  = (const float*)d_in[0];
    const int*   ei = (const int*)d_in[1];
    const float* W1 = (const float*)d_in[2];
    const float* b1 = (const float*)d_in[3];
    const float* W2 = (const float*)d_in[4];
    const float* b2 = (const float*)d_in[5];
    const float* Wc = (const float*)d_in[6];
    const float* bc = (const float*)d_in[7];
    float* out = (float*)d_out;

    char* ws = (char*)d_ws;
    size_t off = 0;
    auto alloc = [&](size_t bytes) {
        void* p = ws + off;
        off += (bytes + 511) & ~(size_t)511;
        return p;
    };
    unsigned char*  hist   = (unsigned char*) alloc((size_t)HB * 50000);     // 6.4MB
    unsigned char*  rank   = (unsigned char*) alloc((size_t)E);              // 0.8MB
    int*            deg    = (int*)           alloc((size_t)N * 4);
    float*          dinv   = (float*)         alloc((size_t)N * 4);
    unsigned short* csr    = (unsigned short*)alloc((size_t)N * CAP * 2);    // 6.4MB
    __half*         hsH    = (__half*)        alloc((size_t)N * D * 2);      // 12.8MB
    __half*         hactH  = (__half*)        alloc((size_t)N * D * 2);      // 12.8MB
    __half*         Wt1    = (__half*)        alloc((size_t)D * D * 2);      // 32KB
    __half*         Wt2    = (__half*)        alloc((size_t)D * D * 2);      // 32KB
    float*          gpart  = (float*)         alloc((size_t)NW * D * 4);     // 6.4MB
    float*          gpart2 = (float*)         alloc((size_t)256 * D * 4);
    (void)ws_size; (void)in_sizes; (void)n_in; (void)out_size;

    const int* col = ei + E;

    k_wt<<<32, 256, 0, stream>>>(W1, W2, Wt1, Wt2);
    k_hist<<<HB, 1024, 0, stream>>>(col, hist, rank);
    k_colscan<<<(N + 255) / 256, 256, 0, stream>>>(hist, deg, dinv);
    // parallel scatter (2/3 of blocks) + MFMA gemm layer 1 (1/3)
    k_fuse<<<GF, 256, 0, stream>>>(ei, hist, rank, csr, x, Wt1, dinv, hsH);

    k_agg1<<<NW, 256, 0, stream>>>(hsH, deg, csr, b1, hactH);
    k_gemm<<<GM, 256, 0, stream>>>(hactH, Wt2, dinv, hsH);
    k_agg2<<<NW, 256, 0, stream>>>(hsH, deg, csr, b2, gpart);
    k_pool<<<256, 256, 0, stream>>>(gpart, gpart2);
    k_final<<<1, 512, 0, stream>>>(gpart2, Wc, bc, out);
}